// Round 5
// baseline (739.209 us; speedup 1.0000x reference)
//
#include <hip/hip_runtime.h>

typedef unsigned short ushort_t;
typedef __attribute__((ext_vector_type(4))) float f32x4;
typedef __attribute__((ext_vector_type(8))) short bf16x8;

constexpr int NN = 10000;       // nodes
constexpr int NE = 160000;      // edges
constexpr int NG = 64;          // graphs
constexpr int NODE_IN_D = 115;
constexpr int EDGE_IN_D = 14;
constexpr int H = 256;
constexpr int UH = 64;
constexpr int DEPTH_D = 5;
constexpr float BN_EPS_F = 1e-5f;

// bf16 helpers
__device__ __forceinline__ float b2fs(ushort_t u) {
  union { unsigned i; float f; } v; v.i = ((unsigned)u) << 16; return v.f;
}
__device__ __forceinline__ ushort_t f2b(float f) {
  union { float f; unsigned i; } v; v.f = f;
  unsigned x = v.i;
  unsigned r = (x + 0x7fffu + ((x >> 16) & 1u)) >> 16;
  return (ushort_t)r;
}

// ---------------------------------------------------------------------------
// edge sort by dst
// ---------------------------------------------------------------------------
__global__ __launch_bounds__(256) void k_hist(const int* __restrict__ dst,
                                              int* __restrict__ deg)
{
  int j = blockIdx.x * 256 + threadIdx.x;
  if (j < NE) atomicAdd(&deg[dst[j]], 1);
}

__global__ __launch_bounds__(256) void k_scan(const int* __restrict__ deg,
    int* __restrict__ row_ptr, int* __restrict__ cursor)
{
  __shared__ int part[256];
  const int t = threadIdx.x;
  const int base = t * 40;
  int s = 0;
  for (int i = 0; i < 40; ++i) {
    int idx = base + i;
    if (idx < NN) s += deg[idx];
  }
  part[t] = s;
  __syncthreads();
  for (int off = 1; off < 256; off <<= 1) {
    int v = (t >= off) ? part[t - off] : 0;
    __syncthreads();
    part[t] += v;
    __syncthreads();
  }
  int run = (t > 0) ? part[t - 1] : 0;
  for (int i = 0; i < 40; ++i) {
    int idx = base + i;
    if (idx < NN) {
      row_ptr[idx] = run;
      cursor[idx]  = run;
      run += deg[idx];
    }
  }
  if (t == 255) row_ptr[NN] = NE;
}

__global__ __launch_bounds__(256) void k_scatter(const int* __restrict__ src,
    const int* __restrict__ dst, int* __restrict__ cursor,
    int* __restrict__ perm, int* __restrict__ src_p, int* __restrict__ dst_p)
{
  int j = blockIdx.x * 256 + threadIdx.x;
  if (j < NE) {
    int d = dst[j];
    int pos = atomicAdd(&cursor[d], 1);
    perm[pos] = j;
    src_p[pos] = src[j];
    dst_p[pos] = d;
  }
}

// ---------------------------------------------------------------------------
// e_p[i,:] = edge_attr[perm[i]] @ ep_w + ep_b   (bf16, dst-sorted)
// ---------------------------------------------------------------------------
__global__ __launch_bounds__(256) void k_proj_edge(const float* __restrict__ ea,
    const int* __restrict__ perm,
    const float* __restrict__ w, const float* __restrict__ b,
    ushort_t* __restrict__ e_p)
{
  __shared__ float as[16][EDGE_IN_D];
  __shared__ int pj[16];
  const int t = threadIdx.x;
  const int row0 = blockIdx.x * 16;
  if (t < 16) pj[t] = perm[row0 + t];
  __syncthreads();
  if (t < 16 * EDGE_IN_D) {
    int r = t / EDGE_IN_D, c = t - r * EDGE_IN_D;
    as[r][c] = ea[(size_t)pj[r] * EDGE_IN_D + c];
  }
  __syncthreads();
  float acc[16];
#pragma unroll
  for (int m = 0; m < 16; ++m) acc[m] = 0.f;
  for (int k = 0; k < EDGE_IN_D; ++k) {
    float wv = w[(size_t)k * H + t];
#pragma unroll
    for (int m = 0; m < 16; ++m) acc[m] += as[m][k] * wv;
  }
  const float bv = b[t];
  for (int m = 0; m < 16; ++m)
    e_p[(size_t)(row0 + m) * H + t] = f2b(acc[m] + bv);
}

// ---------------------------------------------------------------------------
// Pack ALL weights into MFMA B-fragment order.
// per depth: wc 2048 | w2 2048 | cw1 8192 | cw2 8192 | pab 4096  (24576)
// tail: xp_w (K padded 115->128): 4096 frags
// ---------------------------------------------------------------------------
__global__ __launch_bounds__(256) void k_pack_all(
    const float* __restrict__ uw1, const float* __restrict__ uw2,
    const float* __restrict__ cw1, const float* __restrict__ cw2,
    const float* __restrict__ xp_w,
    ushort_t* __restrict__ wcP, ushort_t* __restrict__ w2P,
    ushort_t* __restrict__ c1P, ushort_t* __restrict__ c2P,
    ushort_t* __restrict__ pabP, ushort_t* __restrict__ xpP)
{
  int od = blockIdx.x * 256 + threadIdx.x;
  if (od >= DEPTH_D * 24576) {
    int r = od - DEPTH_D * 24576;
    if (r >= 4096) return;
    int lane = r & 63; int nk = r >> 6;
    int ks = nk & 3, nt = nk >> 2;
    int kbase = ks * 32 + (lane >> 4) * 8;
    int n = nt * 16 + (lane & 15);
    ushort_t v[8];
#pragma unroll
    for (int j = 0; j < 8; ++j) {
      int k = kbase + j;
      v[j] = (k < NODE_IN_D) ? f2b(xp_w[(size_t)k * H + n]) : (ushort_t)0;
    }
    uint4 o;
    o.x = (unsigned)v[0] | ((unsigned)v[1] << 16);
    o.y = (unsigned)v[2] | ((unsigned)v[3] << 16);
    o.z = (unsigned)v[4] | ((unsigned)v[5] << 16);
    o.w = (unsigned)v[6] | ((unsigned)v[7] << 16);
    *(uint4*)(xpP + (size_t)r * 8) = o;
    return;
  }
  int depth = od / 24576;
  int r = od - depth * 24576;
  const float* w1d = uw1 + (size_t)depth * 768 * 64;
  const float* W = nullptr; ushort_t* out = nullptr;
  int N = 0, KS = 8; bool pab = false;
  if (r < 2048)       { W = w1d + 512 * 64; out = wcP + (size_t)depth * 2048 * 8; N = 64; KS = 8; }
  else if (r < 4096)  { r -= 2048;  W = uw2 + (size_t)depth * 64 * 256;  out = w2P + (size_t)depth * 2048 * 8; N = 256; KS = 2; }
  else if (r < 12288) { r -= 4096;  W = cw1 + (size_t)depth * 256 * 256; out = c1P + (size_t)depth * 8192 * 8; N = 256; KS = 8; }
  else if (r < 20480) { r -= 12288; W = cw2 + (size_t)depth * 256 * 256; out = c2P + (size_t)depth * 8192 * 8; N = 256; KS = 8; }
  else                { r -= 20480; out = pabP + (size_t)depth * 4096 * 8; N = 128; KS = 8; pab = true; }
  int lane = r & 63; int nk = r >> 6;
  int ks = nk % KS, nt = nk / KS;
  int kbase = ks * 32 + (lane >> 4) * 8;
  int n = nt * 16 + (lane & 15);
  ushort_t v[8];
#pragma unroll
  for (int j = 0; j < 8; ++j) {
    int k = kbase + j;
    float xv;
    if (!pab) xv = W[(size_t)k * N + n];
    else      xv = (n < 64) ? w1d[(size_t)k * 64 + n]
                            : w1d[(size_t)(256 + k) * 64 + (n - 64)];
    v[j] = f2b(xv);
  }
  uint4 o;
  o.x = (unsigned)v[0] | ((unsigned)v[1] << 16);
  o.y = (unsigned)v[2] | ((unsigned)v[3] << 16);
  o.z = (unsigned)v[4] | ((unsigned)v[5] << 16);
  o.w = (unsigned)v[6] | ((unsigned)v[7] << 16);
  *(uint4*)(out + (size_t)r * 8) = o;
}

// ---------------------------------------------------------------------------
// k_projm: xb = x @ xp_w + xp_b (MFMA, K pad 128, hi/lo split A)
//          + fused Pab(depth 0)
// ---------------------------------------------------------------------------
__global__ __launch_bounds__(256) void k_projm(const float* __restrict__ x,
    const ushort_t* __restrict__ xpP, const float* __restrict__ xpb,
    const ushort_t* __restrict__ pabP0,
    float* __restrict__ xb, float* __restrict__ Pab)
{
  __shared__ __align__(16) ushort_t sa[2 * 32 * 128];   // x hi/lo, 16 KB
  __shared__ __align__(16) ushort_t sx[2 * 32 * 256];   // xb hi/lo, 32 KB
  const int t = threadIdx.x, l = t & 63, w = t >> 6;
  const int row0 = blockIdx.x * 32;
#pragma unroll
  for (int it = 0; it < 16; ++it) {
    int idx = t + it * 256;          // 4096 = 32*128
    int row = idx >> 7, c = idx & 127;
    int grow = row0 + row;
    float v = (grow < NN && c < NODE_IN_D) ? x[(size_t)grow * NODE_IN_D + c] : 0.f;
    ushort_t h = f2b(v);
    ushort_t lo = f2b(v - b2fs(h));
    int sch = (row * 16 + ((c >> 3) ^ (row & 7))) * 8 + (c & 7);
    sa[sch] = h; sa[4096 + sch] = lo;
  }
  __syncthreads();
  const int mt = w & 1, ntb = (w >> 1) * 8;
  const int lrow = l & 15, lhi = l >> 4;
  const int arow = mt * 16 + lrow, sw = arow & 7;
  f32x4 acc[8];
#pragma unroll
  for (int n = 0; n < 8; ++n) acc[n] = (f32x4){0.f, 0.f, 0.f, 0.f};
#pragma unroll
  for (int ks = 0; ks < 4; ++ks) {
    int sch = (arow * 16 + ((ks * 4 + lhi) ^ sw)) * 8;
    bf16x8 ah = *(const bf16x8*)&sa[sch];
    bf16x8 al = *(const bf16x8*)&sa[4096 + sch];
#pragma unroll
    for (int n = 0; n < 8; ++n) {
      bf16x8 bb = *(const bf16x8*)(xpP + (size_t)(((ntb + n) * 4 + ks) * 64 + l) * 8);
      acc[n] = __builtin_amdgcn_mfma_f32_16x16x32_bf16(ah, bb, acc[n], 0, 0, 0);
      acc[n] = __builtin_amdgcn_mfma_f32_16x16x32_bf16(al, bb, acc[n], 0, 0, 0);
    }
  }
#pragma unroll
  for (int n = 0; n < 8; ++n) {
    int col = (ntb + n) * 16 + lrow;
    float bv = xpb[col];
#pragma unroll
    for (int r = 0; r < 4; ++r) {
      int row = mt * 16 + lhi * 4 + r;
      int grow = row0 + row;
      float v = acc[n][r] + bv;
      if (grow < NN) xb[(size_t)grow * H + col] = v;
      ushort_t h = f2b(v);
      ushort_t lo = f2b(v - b2fs(h));
      int sch = (row * 32 + ((col >> 3) ^ (row & 7))) * 8 + (col & 7);
      sx[sch] = h; sx[8192 + sch] = lo;
    }
  }
  __syncthreads();
  const int ntb2 = (w >> 1) * 4;
  f32x4 pacc[4];
#pragma unroll
  for (int n = 0; n < 4; ++n) pacc[n] = (f32x4){0.f, 0.f, 0.f, 0.f};
#pragma unroll
  for (int ks = 0; ks < 8; ++ks) {
    int sch = (arow * 32 + ((ks * 4 + lhi) ^ sw)) * 8;
    bf16x8 ah = *(const bf16x8*)&sx[sch];
    bf16x8 al = *(const bf16x8*)&sx[8192 + sch];
#pragma unroll
    for (int n = 0; n < 4; ++n) {
      bf16x8 bb = *(const bf16x8*)(pabP0 + (size_t)(((ntb2 + n) * 8 + ks) * 64 + l) * 8);
      pacc[n] = __builtin_amdgcn_mfma_f32_16x16x32_bf16(ah, bb, pacc[n], 0, 0, 0);
      pacc[n] = __builtin_amdgcn_mfma_f32_16x16x32_bf16(al, bb, pacc[n], 0, 0, 0);
    }
  }
#pragma unroll
  for (int n = 0; n < 4; ++n) {
    int col = (ntb2 + n) * 16 + lrow;
#pragma unroll
    for (int r = 0; r < 4; ++r) {
      int row = mt * 16 + lhi * 4 + r;
      int grow = row0 + row;
      if (grow < NN) Pab[(size_t)grow * 128 + col] = pacc[n][r];
    }
  }
}

// ---------------------------------------------------------------------------
// MFMA edge kernel + FUSED aggregation epilogue.
// 64 edges/block (dst-sorted), 4 waves; wave w owns rows 16w..16w+15.
// phase1: h = relu(e@Wc + Pa[src] + Pb[dst] + b1)
// phase2: e_new = e + h@w2 + b2 (write back iff write_e)
// epilogue: segmented sum of relu(xb[src]+e_new) by dst -> atomicAdd agg
// ---------------------------------------------------------------------------
__global__ __launch_bounds__(256) void k_edge_mfma(
    const float* __restrict__ Pab,
    const int* __restrict__ src_p, const int* __restrict__ dst_p,
    const ushort_t* __restrict__ wcP, const float* __restrict__ b1,
    const ushort_t* __restrict__ w2P, const float* __restrict__ b2,
    ushort_t* __restrict__ e_p,
    const float* __restrict__ xb, float* __restrict__ agg, int write_e)
{
  __shared__ __align__(16) ushort_t es[64 * 256];   // 32 KB, col ^= (row&7)<<3
  __shared__ __align__(16) ushort_t hsm[64 * 64];   // 8 KB
  __shared__ int sid[64], did[64];
  const int t = threadIdx.x;
  const int l = t & 63;
  const int w = t >> 6;
  const int e0 = blockIdx.x * 64;
  if (t < 64) { sid[t] = src_p[e0 + t]; did[t] = dst_p[e0 + t]; }
#pragma unroll
  for (int it = 0; it < 8; ++it) {
    int idx = t + it * 256;
    int row = idx >> 5, ch = idx & 31;
    uint4 v = *(const uint4*)(e_p + (size_t)(e0 + row) * H + ch * 8);
    *(uint4*)&es[(row * 32 + (ch ^ (row & 7))) * 8] = v;
  }
  __syncthreads();

  const int rw = w * 16;
  const int lrow = l & 15, lhi = l >> 4;

  bf16x8 af[8];
  {
    int arow = rw + lrow;
    int sw = arow & 7;
#pragma unroll
    for (int ks = 0; ks < 8; ++ks)
      af[ks] = *(const bf16x8*)&es[(arow * 32 + ((ks * 4 + lhi) ^ sw)) * 8];
  }
  f32x4 acc[4];
#pragma unroll
  for (int nt = 0; nt < 4; ++nt) {
    f32x4 a = {0.f, 0.f, 0.f, 0.f};
#pragma unroll
    for (int ks = 0; ks < 8; ++ks) {
      bf16x8 bb = *(const bf16x8*)(wcP + (size_t)((nt * 8 + ks) * 64 + l) * 8);
      a = __builtin_amdgcn_mfma_f32_16x16x32_bf16(af[ks], bb, a, 0, 0, 0);
    }
    acc[nt] = a;
  }
#pragma unroll
  for (int nt = 0; nt < 4; ++nt) {
    int col = nt * 16 + lrow;
    float bv = b1[col];
#pragma unroll
    for (int r = 0; r < 4; ++r) {
      int row = rw + lhi * 4 + r;
      float v = acc[nt][r] + Pab[(size_t)sid[row] * 128 + col]
                           + Pab[(size_t)did[row] * 128 + 64 + col] + bv;
      hsm[row * 64 + (col ^ ((row & 7) << 3))] = f2b(fmaxf(v, 0.f));
    }
  }
  __syncthreads();

  bf16x8 ag[2];
  {
    int arow = rw + lrow;
    int sw = arow & 7;
#pragma unroll
    for (int ks = 0; ks < 2; ++ks)
      ag[ks] = *(const bf16x8*)&hsm[arow * 64 + (((ks * 4 + lhi) ^ sw)) * 8];
  }
#pragma unroll
  for (int nt = 0; nt < 16; ++nt) {
    int col = nt * 16 + lrow;
    float bv = b2[col];
    f32x4 a;
#pragma unroll
    for (int r = 0; r < 4; ++r) {
      int row = rw + lhi * 4 + r;
      a[r] = b2fs(es[row * 256 + (col ^ ((row & 7) << 3))]) + bv;
    }
    bf16x8 bb0 = *(const bf16x8*)(w2P + (size_t)((nt * 2 + 0) * 64 + l) * 8);
    bf16x8 bb1 = *(const bf16x8*)(w2P + (size_t)((nt * 2 + 1) * 64 + l) * 8);
    a = __builtin_amdgcn_mfma_f32_16x16x32_bf16(ag[0], bb0, a, 0, 0, 0);
    a = __builtin_amdgcn_mfma_f32_16x16x32_bf16(ag[1], bb1, a, 0, 0, 0);
#pragma unroll
    for (int r = 0; r < 4; ++r) {
      int row = rw + lhi * 4 + r;
      es[row * 256 + (col ^ ((row & 7) << 3))] = f2b(a[r]);
    }
  }
  __syncthreads();

  if (write_e) {
#pragma unroll
    for (int it = 0; it < 8; ++it) {
      int idx = t + it * 256;
      int row = idx >> 5, ch = idx & 31;
      uint4 v = *(const uint4*)&es[(row * 32 + (ch ^ (row & 7))) * 8];
      *(uint4*)(e_p + (size_t)(e0 + row) * H + ch * 8) = v;
    }
  }

  // ---- fused aggregation: wave w processes edges rw..rw+15, lane l = cols 4l..4l+3
  {
    const int c0 = l * 4;
    float4 acc4 = make_float4(0.f, 0.f, 0.f, 0.f);
    int cur = did[rw];
#pragma unroll
    for (int r = 0; r < 16; ++r) {
      int row = rw + r;
      int d = did[row];                 // wave-uniform
      if (d != cur) {
        float* gp = agg + (size_t)cur * H + c0;
        atomicAdd(gp + 0, acc4.x); atomicAdd(gp + 1, acc4.y);
        atomicAdd(gp + 2, acc4.z); atomicAdd(gp + 3, acc4.w);
        acc4 = make_float4(0.f, 0.f, 0.f, 0.f);
        cur = d;
      }
      ushort4 ev = *(const ushort4*)&es[row * 256 + (c0 ^ ((row & 7) << 3))];
      float4 xv = *(const float4*)(xb + (size_t)sid[row] * H + c0);
      acc4.x += fmaxf(xv.x + b2fs(ev.x), 0.f);
      acc4.y += fmaxf(xv.y + b2fs(ev.y), 0.f);
      acc4.z += fmaxf(xv.z + b2fs(ev.z), 0.f);
      acc4.w += fmaxf(xv.w + b2fs(ev.w), 0.f);
    }
    float* gp = agg + (size_t)cur * H + c0;
    atomicAdd(gp + 0, acc4.x); atomicAdd(gp + 1, acc4.y);
    atomicAdd(gp + 2, acc4.z); atomicAdd(gp + 3, acc4.w);
  }
}

// ---------------------------------------------------------------------------
// Fused conv: t1 = relu((xb+agg)@cw1+cb1) [LDS] ; z = BN(t1@cw2+cb2);
// xb += relu(z); optional fused Pab(next depth).  16 rows/block.
// ---------------------------------------------------------------------------
__global__ __launch_bounds__(256) void k_convm(
    const float* __restrict__ agg,
    const ushort_t* __restrict__ w1P, const float* __restrict__ b1v,
    const ushort_t* __restrict__ w2P, const float* __restrict__ cb2v,
    const float* __restrict__ bng, const float* __restrict__ bnb,
    const float* __restrict__ bnm, const float* __restrict__ bnv,
    float* __restrict__ xb, int do_pab,
    const ushort_t* __restrict__ pabPn, float* __restrict__ Pab)
{
  __shared__ __align__(16) ushort_t sm[2 * 16 * 256];   // in hi/lo, reused xb_new hi/lo
  __shared__ __align__(16) ushort_t st1[2 * 16 * 256];  // t1 hi/lo
  __shared__ __align__(16) float outs[16 * 256];        // pre-BN z
  const int t = threadIdx.x, l = t & 63, w = t >> 6;
  const int row0 = blockIdx.x * 16;
  // stage xb+agg, hi/lo split
#pragma unroll
  for (int it = 0; it < 2; ++it) {
    int idx = t + it * 256;
    int row = idx >> 5, ch = idx & 31;
    int grow = row0 + row;
    float4 p = *(const float4*)(xb + (size_t)grow * H + ch * 8);
    float4 q = *(const float4*)(xb + (size_t)grow * H + ch * 8 + 4);
    float4 g = *(const float4*)(agg + (size_t)grow * H + ch * 8);
    float4 h4 = *(const float4*)(agg + (size_t)grow * H + ch * 8 + 4);
    float v[8] = {p.x + g.x, p.y + g.y, p.z + g.z, p.w + g.w,
                  q.x + h4.x, q.y + h4.y, q.z + h4.z, q.w + h4.w};
    ushort_t h8[8], l8[8];
#pragma unroll
    for (int j = 0; j < 8; ++j) { h8[j] = f2b(v[j]); l8[j] = f2b(v[j] - b2fs(h8[j])); }
    uint4 hh, ll;
    hh.x = (unsigned)h8[0] | ((unsigned)h8[1] << 16);
    hh.y = (unsigned)h8[2] | ((unsigned)h8[3] << 16);
    hh.z = (unsigned)h8[4] | ((unsigned)h8[5] << 16);
    hh.w = (unsigned)h8[6] | ((unsigned)h8[7] << 16);
    ll.x = (unsigned)l8[0] | ((unsigned)l8[1] << 16);
    ll.y = (unsigned)l8[2] | ((unsigned)l8[3] << 16);
    ll.z = (unsigned)l8[4] | ((unsigned)l8[5] << 16);
    ll.w = (unsigned)l8[6] | ((unsigned)l8[7] << 16);
    int sch = (row * 32 + (ch ^ (row & 7))) * 8;
    *(uint4*)&sm[sch] = hh;
    *(uint4*)&sm[4096 + sch] = ll;
  }
  __syncthreads();
  const int lrow = l & 15, lhi = l >> 4;
  const int arow = lrow, sw = arow & 7;
  const int ntb = w * 4;
  // MFMA pass 1
  f32x4 acc[4];
#pragma unroll
  for (int n = 0; n < 4; ++n) acc[n] = (f32x4){0.f, 0.f, 0.f, 0.f};
#pragma unroll
  for (int ks = 0; ks < 8; ++ks) {
    int sch = (arow * 32 + ((ks * 4 + lhi) ^ sw)) * 8;
    bf16x8 ah = *(const bf16x8*)&sm[sch];
    bf16x8 al = *(const bf16x8*)&sm[4096 + sch];
#pragma unroll
    for (int n = 0; n < 4; ++n) {
      bf16x8 bb = *(const bf16x8*)(w1P + (size_t)(((ntb + n) * 8 + ks) * 64 + l) * 8);
      acc[n] = __builtin_amdgcn_mfma_f32_16x16x32_bf16(ah, bb, acc[n], 0, 0, 0);
      acc[n] = __builtin_amdgcn_mfma_f32_16x16x32_bf16(al, bb, acc[n], 0, 0, 0);
    }
  }
  // t1 = relu(acc+b) -> st1 hi/lo (swizzled)
#pragma unroll
  for (int n = 0; n < 4; ++n) {
    int col = (ntb + n) * 16 + lrow;
    float bv = b1v[col];
#pragma unroll
    for (int r = 0; r < 4; ++r) {
      int row = lhi * 4 + r;
      float v = fmaxf(acc[n][r] + bv, 0.f);
      ushort_t h = f2b(v);
      ushort_t lo = f2b(v - b2fs(h));
      int sch = (row * 32 + ((col >> 3) ^ (row & 7))) * 8 + (col & 7);
      st1[sch] = h; st1[4096 + sch] = lo;
    }
  }
  __syncthreads();
  // MFMA pass 2
  f32x4 acc2[4];
#pragma unroll
  for (int n = 0; n < 4; ++n) acc2[n] = (f32x4){0.f, 0.f, 0.f, 0.f};
#pragma unroll
  for (int ks = 0; ks < 8; ++ks) {
    int sch = (arow * 32 + ((ks * 4 + lhi) ^ sw)) * 8;
    bf16x8 ah = *(const bf16x8*)&st1[sch];
    bf16x8 al = *(const bf16x8*)&st1[4096 + sch];
#pragma unroll
    for (int n = 0; n < 4; ++n) {
      bf16x8 bb = *(const bf16x8*)(w2P + (size_t)(((ntb + n) * 8 + ks) * 64 + l) * 8);
      acc2[n] = __builtin_amdgcn_mfma_f32_16x16x32_bf16(ah, bb, acc2[n], 0, 0, 0);
      acc2[n] = __builtin_amdgcn_mfma_f32_16x16x32_bf16(al, bb, acc2[n], 0, 0, 0);
    }
  }
#pragma unroll
  for (int n = 0; n < 4; ++n) {
    int col = (ntb + n) * 16 + lrow;
    float bv = cb2v[col];
#pragma unroll
    for (int r = 0; r < 4; ++r)
      outs[(lhi * 4 + r) * 256 + col] = acc2[n][r] + bv;
  }
  __syncthreads();
  // BN + residual + xb write + optional sx refill (reuse sm)
#pragma unroll
  for (int it = 0; it < 4; ++it) {
    int idx = t + it * 256;
    int row = idx >> 6, c4 = idx & 63;
    int grow = row0 + row;
    int c0 = c4 * 4;
    float4 z = *(float4*)&outs[row * 256 + c0];
    float4 g4 = *(const float4*)(bng + c0);
    float4 b4 = *(const float4*)(bnb + c0);
    float4 m4 = *(const float4*)(bnm + c0);
    float4 v4 = *(const float4*)(bnv + c0);
    float4 xv = *(const float4*)(xb + (size_t)grow * H + c0);
    xv.x += fmaxf((z.x - m4.x) * rsqrtf(v4.x + BN_EPS_F) * g4.x + b4.x, 0.f);
    xv.y += fmaxf((z.y - m4.y) * rsqrtf(v4.y + BN_EPS_F) * g4.y + b4.y, 0.f);
    xv.z += fmaxf((z.z - m4.z) * rsqrtf(v4.z + BN_EPS_F) * g4.z + b4.z, 0.f);
    xv.w += fmaxf((z.w - m4.w) * rsqrtf(v4.w + BN_EPS_F) * g4.w + b4.w, 0.f);
    *(float4*)(xb + (size_t)grow * H + c0) = xv;
    if (do_pab) {
      float vv[4] = {xv.x, xv.y, xv.z, xv.w};
      ushort_t h8[4], l8[4];
#pragma unroll
      for (int j = 0; j < 4; ++j) { h8[j] = f2b(vv[j]); l8[j] = f2b(vv[j] - b2fs(h8[j])); }
      ushort4 hh, ll;
      hh.x = h8[0]; hh.y = h8[1]; hh.z = h8[2]; hh.w = h8[3];
      ll.x = l8[0]; ll.y = l8[1]; ll.z = l8[2]; ll.w = l8[3];
      int sch = (row * 32 + ((c0 >> 3) ^ (row & 7))) * 8 + (c0 & 7);
      *(ushort4*)&sm[sch] = hh;
      *(ushort4*)&sm[4096 + sch] = ll;
    }
  }
  if (!do_pab) return;
  __syncthreads();
  const int ntb2 = w * 2;
  f32x4 pacc[2];
#pragma unroll
  for (int n = 0; n < 2; ++n) pacc[n] = (f32x4){0.f, 0.f, 0.f, 0.f};
#pragma unroll
  for (int ks = 0; ks < 8; ++ks) {
    int sch = (arow * 32 + ((ks * 4 + lhi) ^ sw)) * 8;
    bf16x8 ah = *(const bf16x8*)&sm[sch];
    bf16x8 al = *(const bf16x8*)&sm[4096 + sch];
#pragma unroll
    for (int n = 0; n < 2; ++n) {
      bf16x8 bb = *(const bf16x8*)(pabPn + (size_t)(((ntb2 + n) * 8 + ks) * 64 + l) * 8);
      pacc[n] = __builtin_amdgcn_mfma_f32_16x16x32_bf16(ah, bb, pacc[n], 0, 0, 0);
      pacc[n] = __builtin_amdgcn_mfma_f32_16x16x32_bf16(al, bb, pacc[n], 0, 0, 0);
    }
  }
#pragma unroll
  for (int n = 0; n < 2; ++n) {
    int col = (ntb2 + n) * 16 + lrow;
#pragma unroll
    for (int r = 0; r < 4; ++r)
      Pab[(size_t)(row0 + lhi * 4 + r) * 128 + col] = pacc[n][r];
  }
}

// ---------------------------------------------------------------------------
// pooling
// ---------------------------------------------------------------------------
__global__ void k_count2(const int* __restrict__ batch, float* __restrict__ gcnt)
{
  int g = threadIdx.x;
  int lo = 0, hi = NN;
  while (lo < hi) { int m = (lo + hi) >> 1; if (batch[m] < g) lo = m + 1; else hi = m; }
  int s = lo;
  lo = 0; hi = NN;
  while (lo < hi) { int m = (lo + hi) >> 1; if (batch[m] <= g) lo = m + 1; else hi = m; }
  gcnt[g] = (float)(lo - s);
}

__global__ __launch_bounds__(256) void k_pool(const float* __restrict__ xb,
    const int* __restrict__ batch, float* __restrict__ gsum)
{
  const int t = threadIdx.x;
  const int row0 = blockIdx.x * 32;
  const int c0 = (t & 63) * 4;
  const int rb = (t >> 6) * 8;
  float4 sum = make_float4(0.f, 0.f, 0.f, 0.f);
  int curg = -1;
#pragma unroll
  for (int j = 0; j < 8; ++j) {
    int row = row0 + rb + j;
    if (row < NN) {
      int g = batch[row];
      if (g != curg) {
        if (curg >= 0) {
          float* gp = gsum + (size_t)curg * H + c0;
          atomicAdd(gp + 0, sum.x); atomicAdd(gp + 1, sum.y);
          atomicAdd(gp + 2, sum.z); atomicAdd(gp + 3, sum.w);
        }
        curg = g;
        sum = make_float4(0.f, 0.f, 0.f, 0.f);
      }
      float4 v = *(const float4*)(xb + (size_t)row * H + c0);
      sum.x += v.x; sum.y += v.y; sum.z += v.z; sum.w += v.w;
    }
  }
  if (curg >= 0) {
    float* gp = gsum + (size_t)curg * H + c0;
    atomicAdd(gp + 0, sum.x); atomicAdd(gp + 1, sum.y);
    atomicAdd(gp + 2, sum.z); atomicAdd(gp + 3, sum.w);
  }
}

__global__ __launch_bounds__(256) void k_readout(const float* __restrict__ gsum,
    const float* __restrict__ gcnt, const float* __restrict__ w,
    const float* __restrict__ b, float* __restrict__ out)
{
  __shared__ float gs[H];
  const int g = blockIdx.x;
  const int t = threadIdx.x;
  float cnt = fmaxf(gcnt[g], 1.0f);
  gs[t] = gsum[(size_t)g * H + t] / cnt;
  __syncthreads();
  float acc = 0.f;
  for (int k = 0; k < H; ++k) acc += gs[k] * w[(size_t)k * H + t];
  out[(size_t)g * H + t] = fmaxf(acc + b[t], 0.f);
}

// ---------------------------------------------------------------------------
extern "C" void kernel_launch(void* const* d_in, const int* in_sizes, int n_in,
                              void* d_out, int out_size, void* d_ws, size_t ws_size,
                              hipStream_t stream) {
  (void)in_sizes; (void)n_in; (void)out_size; (void)ws_size;
  const float* x    = (const float*)d_in[0];
  const int*   ei   = (const int*)d_in[1];
  const float* ea   = (const float*)d_in[2];
  const int*   batch= (const int*)d_in[3];
  const float* xp_w = (const float*)d_in[4];
  const float* xp_b = (const float*)d_in[5];
  const float* ep_w = (const float*)d_in[6];
  const float* ep_b = (const float*)d_in[7];
  const float* uw1  = (const float*)d_in[8];
  const float* ub1  = (const float*)d_in[9];
  const float* uw2  = (const float*)d_in[10];
  const float* ub2  = (const float*)d_in[11];
  const float* cw1  = (const float*)d_in[12];
  const float* cb1  = (const float*)d_in[13];
  const float* cw2  = (const float*)d_in[14];
  const float* cb2  = (const float*)d_in[15];
  const float* bng  = (const float*)d_in[16];
  const float* bnb  = (const float*)d_in[17];
  const float* bnm  = (const float*)d_in[18];
  const float* bnv  = (const float*)d_in[19];
  const float* ro_w = (const float*)d_in[20];
  const float* ro_b = (const float*)d_in[21];
  float* out = (float*)d_out;

  char* ws = (char*)d_ws;
  float* xb   = (float*)ws;                  ws += (size_t)NN * H * 4;
  float* agg  = (float*)ws;                  ws += (size_t)NN * H * 4;
  float* Pab  = (float*)ws;                  ws += (size_t)NN * 128 * 4;
  float* gsum = (float*)ws;                  ws += (size_t)NG * H * 4;
  float* gcnt = (float*)ws;                  ws += 256;
  ushort_t* e_p = (ushort_t*)ws;             ws += (size_t)NE * H * 2;
  int* deg    = (int*)ws;                    ws += (size_t)NN * 4;
  int* row_ptr= (int*)ws;                    ws += (size_t)(NN + 8) * 4;
  int* cursor = (int*)ws;                    ws += (size_t)NN * 4;
  int* perm   = (int*)ws;                    ws += (size_t)NE * 4;
  int* src_p  = (int*)ws;                    ws += (size_t)NE * 4;
  int* dst_p  = (int*)ws;                    ws += (size_t)NE * 4;
  ushort_t* wcP = (ushort_t*)ws;             ws += (size_t)DEPTH_D * 2048 * 8 * 2;
  ushort_t* w2P = (ushort_t*)ws;             ws += (size_t)DEPTH_D * 2048 * 8 * 2;
  ushort_t* c1P = (ushort_t*)ws;             ws += (size_t)DEPTH_D * 8192 * 8 * 2;
  ushort_t* c2P = (ushort_t*)ws;             ws += (size_t)DEPTH_D * 8192 * 8 * 2;
  ushort_t* pabP= (ushort_t*)ws;             ws += (size_t)DEPTH_D * 4096 * 8 * 2;
  ushort_t* xpP = (ushort_t*)ws;             ws += (size_t)4096 * 8 * 2;

  const int* src = ei;
  const int* dst = ei + NE;
  const int EB = NE / 256;                   // 625

  hipMemsetAsync(deg, 0, (size_t)NN * 4, stream);
  k_hist<<<EB, 256, 0, stream>>>(dst, deg);
  k_scan<<<1, 256, 0, stream>>>(deg, row_ptr, cursor);
  k_scatter<<<EB, 256, 0, stream>>>(src, dst, cursor, perm, src_p, dst_p);
  k_pack_all<<<496, 256, 0, stream>>>(uw1, uw2, cw1, cw2, xp_w,
                                      wcP, w2P, c1P, c2P, pabP, xpP);
  k_projm<<<313, 256, 0, stream>>>(x, xpP, xp_b, pabP, xb, Pab);
  k_proj_edge<<<NE / 16, 256, 0, stream>>>(ea, perm, ep_w, ep_b, e_p);

  for (int i = 0; i < DEPTH_D; ++i) {
    hipMemsetAsync(agg, 0, (size_t)NN * H * 4, stream);
    int write_e = (i < DEPTH_D - 1) ? 1 : 0;
    k_edge_mfma<<<NE / 64, 256, 0, stream>>>(
        Pab, src_p, dst_p,
        wcP + (size_t)i * 2048 * 8, ub1 + (size_t)i * UH,
        w2P + (size_t)i * 2048 * 8, ub2 + (size_t)i * H,
        e_p, xb, agg, write_e);
    int do_pab = (i < DEPTH_D - 1) ? 1 : 0;
    k_convm<<<NN / 16, 256, 0, stream>>>(
        agg,
        c1P + (size_t)i * 8192 * 8, cb1 + (size_t)i * H,
        c2P + (size_t)i * 8192 * 8, cb2 + (size_t)i * H,
        bng + (size_t)i * H, bnb + (size_t)i * H,
        bnm + (size_t)i * H, bnv + (size_t)i * H,
        xb, do_pab,
        pabP + (size_t)(i + 1 < DEPTH_D ? i + 1 : 0) * 4096 * 8,
        Pab);
  }

  hipMemsetAsync(gsum, 0, (size_t)NG * H * 4, stream);
  k_count2<<<1, 64, 0, stream>>>(batch, gcnt);
  k_pool<<<(NN + 31) / 32, 256, 0, stream>>>(xb, batch, gsum);
  k_readout<<<NG, 256, 0, stream>>>(gsum, gcnt, ro_w, ro_b, out);
}

// Round 6
// 636.269 us; speedup vs baseline: 1.1618x; 1.1618x over previous
//
#include <hip/hip_runtime.h>

typedef unsigned short ushort_t;
typedef __attribute__((ext_vector_type(4))) float f32x4;
typedef __attribute__((ext_vector_type(8))) short bf16x8;

constexpr int NN = 10000;       // nodes
constexpr int NE = 160000;      // edges
constexpr int NG = 64;          // graphs
constexpr int NODE_IN_D = 115;
constexpr int EDGE_IN_D = 14;
constexpr int H = 256;
constexpr int UH = 64;
constexpr int DEPTH_D = 5;
constexpr float BN_EPS_F = 1e-5f;

// bf16 helpers
__device__ __forceinline__ float b2fs(ushort_t u) {
  union { unsigned i; float f; } v; v.i = ((unsigned)u) << 16; return v.f;
}
__device__ __forceinline__ ushort_t f2b(float f) {
  union { float f; unsigned i; } v; v.f = f;
  unsigned x = v.i;
  unsigned r = (x + 0x7fffu + ((x >> 16) & 1u)) >> 16;
  return (ushort_t)r;
}

// ---------------------------------------------------------------------------
// edge sort by dst
// ---------------------------------------------------------------------------
__global__ __launch_bounds__(256) void k_hist(const int* __restrict__ dst,
                                              int* __restrict__ deg)
{
  int j = blockIdx.x * 256 + threadIdx.x;
  if (j < NE) atomicAdd(&deg[dst[j]], 1);
}

__global__ __launch_bounds__(256) void k_scan(const int* __restrict__ deg,
    int* __restrict__ row_ptr, int* __restrict__ cursor)
{
  __shared__ int part[256];
  const int t = threadIdx.x;
  const int base = t * 40;
  int s = 0;
  for (int i = 0; i < 40; ++i) {
    int idx = base + i;
    if (idx < NN) s += deg[idx];
  }
  part[t] = s;
  __syncthreads();
  for (int off = 1; off < 256; off <<= 1) {
    int v = (t >= off) ? part[t - off] : 0;
    __syncthreads();
    part[t] += v;
    __syncthreads();
  }
  int run = (t > 0) ? part[t - 1] : 0;
  for (int i = 0; i < 40; ++i) {
    int idx = base + i;
    if (idx < NN) {
      row_ptr[idx] = run;
      cursor[idx]  = run;
      run += deg[idx];
    }
  }
  if (t == 255) row_ptr[NN] = NE;
}

__global__ __launch_bounds__(256) void k_scatter(const int* __restrict__ src,
    const int* __restrict__ dst, int* __restrict__ cursor,
    int* __restrict__ perm, int* __restrict__ src_p, int* __restrict__ dst_p)
{
  int j = blockIdx.x * 256 + threadIdx.x;
  if (j < NE) {
    int d = dst[j];
    int pos = atomicAdd(&cursor[d], 1);
    perm[pos] = j;
    src_p[pos] = src[j];
    dst_p[pos] = d;
  }
}

// ---------------------------------------------------------------------------
// e_p[i,:] = edge_attr[perm[i]] @ ep_w + ep_b   (bf16, dst-sorted)
// ---------------------------------------------------------------------------
__global__ __launch_bounds__(256) void k_proj_edge(const float* __restrict__ ea,
    const int* __restrict__ perm,
    const float* __restrict__ w, const float* __restrict__ b,
    ushort_t* __restrict__ e_p)
{
  __shared__ float as[16][EDGE_IN_D];
  __shared__ int pj[16];
  const int t = threadIdx.x;
  const int row0 = blockIdx.x * 16;
  if (t < 16) pj[t] = perm[row0 + t];
  __syncthreads();
  if (t < 16 * EDGE_IN_D) {
    int r = t / EDGE_IN_D, c = t - r * EDGE_IN_D;
    as[r][c] = ea[(size_t)pj[r] * EDGE_IN_D + c];
  }
  __syncthreads();
  float acc[16];
#pragma unroll
  for (int m = 0; m < 16; ++m) acc[m] = 0.f;
  for (int k = 0; k < EDGE_IN_D; ++k) {
    float wv = w[(size_t)k * H + t];
#pragma unroll
    for (int m = 0; m < 16; ++m) acc[m] += as[m][k] * wv;
  }
  const float bv = b[t];
  for (int m = 0; m < 16; ++m)
    e_p[(size_t)(row0 + m) * H + t] = f2b(acc[m] + bv);
}

// ---------------------------------------------------------------------------
// Pack ALL weights into MFMA B-fragment order.
// per depth: wc 2048 | w2 2048 | cw1 8192 | cw2 8192 | pab 4096  (24576)
// tail: xp_w (K padded 115->128): 4096 frags
// ---------------------------------------------------------------------------
__global__ __launch_bounds__(256) void k_pack_all(
    const float* __restrict__ uw1, const float* __restrict__ uw2,
    const float* __restrict__ cw1, const float* __restrict__ cw2,
    const float* __restrict__ xp_w,
    ushort_t* __restrict__ wcP, ushort_t* __restrict__ w2P,
    ushort_t* __restrict__ c1P, ushort_t* __restrict__ c2P,
    ushort_t* __restrict__ pabP, ushort_t* __restrict__ xpP)
{
  int od = blockIdx.x * 256 + threadIdx.x;
  if (od >= DEPTH_D * 24576) {
    int r = od - DEPTH_D * 24576;
    if (r >= 4096) return;
    int lane = r & 63; int nk = r >> 6;
    int ks = nk & 3, nt = nk >> 2;
    int kbase = ks * 32 + (lane >> 4) * 8;
    int n = nt * 16 + (lane & 15);
    ushort_t v[8];
#pragma unroll
    for (int j = 0; j < 8; ++j) {
      int k = kbase + j;
      v[j] = (k < NODE_IN_D) ? f2b(xp_w[(size_t)k * H + n]) : (ushort_t)0;
    }
    uint4 o;
    o.x = (unsigned)v[0] | ((unsigned)v[1] << 16);
    o.y = (unsigned)v[2] | ((unsigned)v[3] << 16);
    o.z = (unsigned)v[4] | ((unsigned)v[5] << 16);
    o.w = (unsigned)v[6] | ((unsigned)v[7] << 16);
    *(uint4*)(xpP + (size_t)r * 8) = o;
    return;
  }
  int depth = od / 24576;
  int r = od - depth * 24576;
  const float* w1d = uw1 + (size_t)depth * 768 * 64;
  const float* W = nullptr; ushort_t* out = nullptr;
  int N = 0, KS = 8; bool pab = false;
  if (r < 2048)       { W = w1d + 512 * 64; out = wcP + (size_t)depth * 2048 * 8; N = 64; KS = 8; }
  else if (r < 4096)  { r -= 2048;  W = uw2 + (size_t)depth * 64 * 256;  out = w2P + (size_t)depth * 2048 * 8; N = 256; KS = 2; }
  else if (r < 12288) { r -= 4096;  W = cw1 + (size_t)depth * 256 * 256; out = c1P + (size_t)depth * 8192 * 8; N = 256; KS = 8; }
  else if (r < 20480) { r -= 12288; W = cw2 + (size_t)depth * 256 * 256; out = c2P + (size_t)depth * 8192 * 8; N = 256; KS = 8; }
  else                { r -= 20480; out = pabP + (size_t)depth * 4096 * 8; N = 128; KS = 8; pab = true; }
  int lane = r & 63; int nk = r >> 6;
  int ks = nk % KS, nt = nk / KS;
  int kbase = ks * 32 + (lane >> 4) * 8;
  int n = nt * 16 + (lane & 15);
  ushort_t v[8];
#pragma unroll
  for (int j = 0; j < 8; ++j) {
    int k = kbase + j;
    float xv;
    if (!pab) xv = W[(size_t)k * N + n];
    else      xv = (n < 64) ? w1d[(size_t)k * 64 + n]
                            : w1d[(size_t)(256 + k) * 64 + (n - 64)];
    v[j] = f2b(xv);
  }
  uint4 o;
  o.x = (unsigned)v[0] | ((unsigned)v[1] << 16);
  o.y = (unsigned)v[2] | ((unsigned)v[3] << 16);
  o.z = (unsigned)v[4] | ((unsigned)v[5] << 16);
  o.w = (unsigned)v[6] | ((unsigned)v[7] << 16);
  *(uint4*)(out + (size_t)r * 8) = o;
}

// ---------------------------------------------------------------------------
// k_projm: xb = x @ xp_w + xp_b (MFMA, K pad 128, hi/lo split A)
//          + fused Pab(depth 0)
// ---------------------------------------------------------------------------
__global__ __launch_bounds__(256) void k_projm(const float* __restrict__ x,
    const ushort_t* __restrict__ xpP, const float* __restrict__ xpb,
    const ushort_t* __restrict__ pabP0,
    float* __restrict__ xb, float* __restrict__ Pab)
{
  __shared__ __align__(16) ushort_t sa[2 * 32 * 128];   // x hi/lo, 16 KB
  __shared__ __align__(16) ushort_t sx[2 * 32 * 256];   // xb hi/lo, 32 KB
  const int t = threadIdx.x, l = t & 63, w = t >> 6;
  const int row0 = blockIdx.x * 32;
#pragma unroll
  for (int it = 0; it < 16; ++it) {
    int idx = t + it * 256;          // 4096 = 32*128
    int row = idx >> 7, c = idx & 127;
    int grow = row0 + row;
    float v = (grow < NN && c < NODE_IN_D) ? x[(size_t)grow * NODE_IN_D + c] : 0.f;
    ushort_t h = f2b(v);
    ushort_t lo = f2b(v - b2fs(h));
    int sch = (row * 16 + ((c >> 3) ^ (row & 7))) * 8 + (c & 7);
    sa[sch] = h; sa[4096 + sch] = lo;
  }
  __syncthreads();
  const int mt = w & 1, ntb = (w >> 1) * 8;
  const int lrow = l & 15, lhi = l >> 4;
  const int arow = mt * 16 + lrow, sw = arow & 7;
  f32x4 acc[8];
#pragma unroll
  for (int n = 0; n < 8; ++n) acc[n] = (f32x4){0.f, 0.f, 0.f, 0.f};
#pragma unroll
  for (int ks = 0; ks < 4; ++ks) {
    int sch = (arow * 16 + ((ks * 4 + lhi) ^ sw)) * 8;
    bf16x8 ah = *(const bf16x8*)&sa[sch];
    bf16x8 al = *(const bf16x8*)&sa[4096 + sch];
#pragma unroll
    for (int n = 0; n < 8; ++n) {
      bf16x8 bb = *(const bf16x8*)(xpP + (size_t)(((ntb + n) * 4 + ks) * 64 + l) * 8);
      acc[n] = __builtin_amdgcn_mfma_f32_16x16x32_bf16(ah, bb, acc[n], 0, 0, 0);
      acc[n] = __builtin_amdgcn_mfma_f32_16x16x32_bf16(al, bb, acc[n], 0, 0, 0);
    }
  }
#pragma unroll
  for (int n = 0; n < 8; ++n) {
    int col = (ntb + n) * 16 + lrow;
    float bv = xpb[col];
#pragma unroll
    for (int r = 0; r < 4; ++r) {
      int row = mt * 16 + lhi * 4 + r;
      int grow = row0 + row;
      float v = acc[n][r] + bv;
      if (grow < NN) xb[(size_t)grow * H + col] = v;
      ushort_t h = f2b(v);
      ushort_t lo = f2b(v - b2fs(h));
      int sch = (row * 32 + ((col >> 3) ^ (row & 7))) * 8 + (col & 7);
      sx[sch] = h; sx[8192 + sch] = lo;
    }
  }
  __syncthreads();
  const int ntb2 = (w >> 1) * 4;
  f32x4 pacc[4];
#pragma unroll
  for (int n = 0; n < 4; ++n) pacc[n] = (f32x4){0.f, 0.f, 0.f, 0.f};
#pragma unroll
  for (int ks = 0; ks < 8; ++ks) {
    int sch = (arow * 32 + ((ks * 4 + lhi) ^ sw)) * 8;
    bf16x8 ah = *(const bf16x8*)&sx[sch];
    bf16x8 al = *(const bf16x8*)&sx[8192 + sch];
#pragma unroll
    for (int n = 0; n < 4; ++n) {
      bf16x8 bb = *(const bf16x8*)(pabP0 + (size_t)(((ntb2 + n) * 8 + ks) * 64 + l) * 8);
      pacc[n] = __builtin_amdgcn_mfma_f32_16x16x32_bf16(ah, bb, pacc[n], 0, 0, 0);
      pacc[n] = __builtin_amdgcn_mfma_f32_16x16x32_bf16(al, bb, pacc[n], 0, 0, 0);
    }
  }
#pragma unroll
  for (int n = 0; n < 4; ++n) {
    int col = (ntb2 + n) * 16 + lrow;
#pragma unroll
    for (int r = 0; r < 4; ++r) {
      int row = mt * 16 + lhi * 4 + r;
      int grow = row0 + row;
      if (grow < NN) Pab[(size_t)grow * 128 + col] = pacc[n][r];
    }
  }
}

// ---------------------------------------------------------------------------
// MFMA edge kernel: 64 edges/block, 4 waves (no fused agg — reverted)
// phase1: h = relu(e@Wc + Pa[src] + Pb[dst] + b1)
// phase2: e = e + h@w2 + b2, write back
// ---------------------------------------------------------------------------
__global__ __launch_bounds__(256) void k_edge_mfma(
    const float* __restrict__ Pab,
    const int* __restrict__ src_p, const int* __restrict__ dst_p,
    const ushort_t* __restrict__ wcP, const float* __restrict__ b1,
    const ushort_t* __restrict__ w2P, const float* __restrict__ b2,
    ushort_t* __restrict__ e_p)
{
  __shared__ __align__(16) ushort_t es[64 * 256];   // 32 KB, chunk^=(row&7)
  __shared__ __align__(16) ushort_t hsm[64 * 64];   // 8 KB
  __shared__ int sid[64], did[64];
  const int t = threadIdx.x;
  const int l = t & 63;
  const int w = t >> 6;
  const int e0 = blockIdx.x * 64;
  if (t < 64) { sid[t] = src_p[e0 + t]; did[t] = dst_p[e0 + t]; }
#pragma unroll
  for (int it = 0; it < 8; ++it) {
    int idx = t + it * 256;
    int row = idx >> 5, ch = idx & 31;
    uint4 v = *(const uint4*)(e_p + (size_t)(e0 + row) * H + ch * 8);
    *(uint4*)&es[(row * 32 + (ch ^ (row & 7))) * 8] = v;
  }
  __syncthreads();

  const int rw = w * 16;
  const int lrow = l & 15, lhi = l >> 4;

  bf16x8 af[8];
  {
    int arow = rw + lrow;
    int sw = arow & 7;
#pragma unroll
    for (int ks = 0; ks < 8; ++ks)
      af[ks] = *(const bf16x8*)&es[(arow * 32 + ((ks * 4 + lhi) ^ sw)) * 8];
  }
  f32x4 acc[4];
#pragma unroll
  for (int nt = 0; nt < 4; ++nt) {
    f32x4 a = {0.f, 0.f, 0.f, 0.f};
#pragma unroll
    for (int ks = 0; ks < 8; ++ks) {
      bf16x8 bb = *(const bf16x8*)(wcP + (size_t)((nt * 8 + ks) * 64 + l) * 8);
      a = __builtin_amdgcn_mfma_f32_16x16x32_bf16(af[ks], bb, a, 0, 0, 0);
    }
    acc[nt] = a;
  }
#pragma unroll
  for (int nt = 0; nt < 4; ++nt) {
    int col = nt * 16 + lrow;
    float bv = b1[col];
#pragma unroll
    for (int r = 0; r < 4; ++r) {
      int row = rw + lhi * 4 + r;
      float v = acc[nt][r] + Pab[(size_t)sid[row] * 128 + col]
                           + Pab[(size_t)did[row] * 128 + 64 + col] + bv;
      hsm[row * 64 + (col ^ ((row & 7) << 3))] = f2b(fmaxf(v, 0.f));
    }
  }
  __syncthreads();

  bf16x8 ag[2];
  {
    int arow = rw + lrow;
    int sw = arow & 7;
#pragma unroll
    for (int ks = 0; ks < 2; ++ks)
      ag[ks] = *(const bf16x8*)&hsm[arow * 64 + (((ks * 4 + lhi) ^ sw)) * 8];
  }
#pragma unroll
  for (int nt = 0; nt < 16; ++nt) {
    int col = nt * 16 + lrow;
    float bv = b2[col];
    f32x4 a;
#pragma unroll
    for (int r = 0; r < 4; ++r) {
      int row = rw + lhi * 4 + r;
      a[r] = b2fs(es[row * 256 + (col ^ ((row & 7) << 3))]) + bv;
    }
    bf16x8 bb0 = *(const bf16x8*)(w2P + (size_t)((nt * 2 + 0) * 64 + l) * 8);
    bf16x8 bb1 = *(const bf16x8*)(w2P + (size_t)((nt * 2 + 1) * 64 + l) * 8);
    a = __builtin_amdgcn_mfma_f32_16x16x32_bf16(ag[0], bb0, a, 0, 0, 0);
    a = __builtin_amdgcn_mfma_f32_16x16x32_bf16(ag[1], bb1, a, 0, 0, 0);
#pragma unroll
    for (int r = 0; r < 4; ++r) {
      int row = rw + lhi * 4 + r;
      es[row * 256 + (col ^ ((row & 7) << 3))] = f2b(a[r]);
    }
  }
  __syncthreads();
#pragma unroll
  for (int it = 0; it < 8; ++it) {
    int idx = t + it * 256;
    int row = idx >> 5, ch = idx & 31;
    uint4 v = *(const uint4*)&es[(row * 32 + (ch ^ (row & 7))) * 8];
    *(uint4*)(e_p + (size_t)(e0 + row) * H + ch * 8) = v;
  }
}

// ---------------------------------------------------------------------------
// agg[n] = sum_{CSR(n)} relu(xb[src]+e)   (no atomics; block = 4 waves/nodes)
// ---------------------------------------------------------------------------
__global__ __launch_bounds__(256) void k_agg(
    const ushort_t* __restrict__ e_p, const float* __restrict__ xb,
    const int* __restrict__ src_p, const int* __restrict__ row_ptr,
    float* __restrict__ agg)
{
  const int t = threadIdx.x;
  const int n = blockIdx.x * 4 + (t >> 6);
  const int c0 = (t & 63) * 4;
  const int beg = row_ptr[n], end = row_ptr[n + 1];
  float4 acc = make_float4(0.f, 0.f, 0.f, 0.f);
  for (int j = beg; j < end; ++j) {
    ushort4 ev = *(const ushort4*)(e_p + (size_t)j * H + c0);
    const float4 xv = *(const float4*)(xb + (size_t)src_p[j] * H + c0);
    acc.x += fmaxf(xv.x + b2fs(ev.x), 0.f);
    acc.y += fmaxf(xv.y + b2fs(ev.y), 0.f);
    acc.z += fmaxf(xv.z + b2fs(ev.z), 0.f);
    acc.w += fmaxf(xv.w + b2fs(ev.w), 0.f);
  }
  *(float4*)(agg + (size_t)n * H + c0) = acc;
}

// ---------------------------------------------------------------------------
// Fused conv: t1 = relu((xb+agg)@cw1+cb1) [LDS] ; z = BN(t1@cw2+cb2);
// xb += relu(z); optional fused Pab(next depth).  16 rows/block.
// ---------------------------------------------------------------------------
__global__ __launch_bounds__(256) void k_convm(
    const float* __restrict__ agg,
    const ushort_t* __restrict__ w1P, const float* __restrict__ b1v,
    const ushort_t* __restrict__ w2P, const float* __restrict__ cb2v,
    const float* __restrict__ bng, const float* __restrict__ bnb,
    const float* __restrict__ bnm, const float* __restrict__ bnv,
    float* __restrict__ xb, int do_pab,
    const ushort_t* __restrict__ pabPn, float* __restrict__ Pab)
{
  __shared__ __align__(16) ushort_t sm[2 * 16 * 256];   // in hi/lo, reused xb_new hi/lo
  __shared__ __align__(16) ushort_t st1[2 * 16 * 256];  // t1 hi/lo
  __shared__ __align__(16) float outs[16 * 256];        // pre-BN z
  const int t = threadIdx.x, l = t & 63, w = t >> 6;
  const int row0 = blockIdx.x * 16;
  // stage xb+agg, hi/lo split
#pragma unroll
  for (int it = 0; it < 2; ++it) {
    int idx = t + it * 256;
    int row = idx >> 5, ch = idx & 31;
    int grow = row0 + row;
    float4 p = *(const float4*)(xb + (size_t)grow * H + ch * 8);
    float4 q = *(const float4*)(xb + (size_t)grow * H + ch * 8 + 4);
    float4 g = *(const float4*)(agg + (size_t)grow * H + ch * 8);
    float4 h4 = *(const float4*)(agg + (size_t)grow * H + ch * 8 + 4);
    float v[8] = {p.x + g.x, p.y + g.y, p.z + g.z, p.w + g.w,
                  q.x + h4.x, q.y + h4.y, q.z + h4.z, q.w + h4.w};
    ushort_t h8[8], l8[8];
#pragma unroll
    for (int j = 0; j < 8; ++j) { h8[j] = f2b(v[j]); l8[j] = f2b(v[j] - b2fs(h8[j])); }
    uint4 hh, ll;
    hh.x = (unsigned)h8[0] | ((unsigned)h8[1] << 16);
    hh.y = (unsigned)h8[2] | ((unsigned)h8[3] << 16);
    hh.z = (unsigned)h8[4] | ((unsigned)h8[5] << 16);
    hh.w = (unsigned)h8[6] | ((unsigned)h8[7] << 16);
    ll.x = (unsigned)l8[0] | ((unsigned)l8[1] << 16);
    ll.y = (unsigned)l8[2] | ((unsigned)l8[3] << 16);
    ll.z = (unsigned)l8[4] | ((unsigned)l8[5] << 16);
    ll.w = (unsigned)l8[6] | ((unsigned)l8[7] << 16);
    int sch = (row * 32 + (ch ^ (row & 7))) * 8;
    *(uint4*)&sm[sch] = hh;
    *(uint4*)&sm[4096 + sch] = ll;
  }
  __syncthreads();
  const int lrow = l & 15, lhi = l >> 4;
  const int arow = lrow, sw = arow & 7;
  const int ntb = w * 4;
  // MFMA pass 1
  f32x4 acc[4];
#pragma unroll
  for (int n = 0; n < 4; ++n) acc[n] = (f32x4){0.f, 0.f, 0.f, 0.f};
#pragma unroll
  for (int ks = 0; ks < 8; ++ks) {
    int sch = (arow * 32 + ((ks * 4 + lhi) ^ sw)) * 8;
    bf16x8 ah = *(const bf16x8*)&sm[sch];
    bf16x8 al = *(const bf16x8*)&sm[4096 + sch];
#pragma unroll
    for (int n = 0; n < 4; ++n) {
      bf16x8 bb = *(const bf16x8*)(w1P + (size_t)(((ntb + n) * 8 + ks) * 64 + l) * 8);
      acc[n] = __builtin_amdgcn_mfma_f32_16x16x32_bf16(ah, bb, acc[n], 0, 0, 0);
      acc[n] = __builtin_amdgcn_mfma_f32_16x16x32_bf16(al, bb, acc[n], 0, 0, 0);
    }
  }
  // t1 = relu(acc+b) -> st1 hi/lo (swizzled)
#pragma unroll
  for (int n = 0; n < 4; ++n) {
    int col = (ntb + n) * 16 + lrow;
    float bv = b1v[col];
#pragma unroll
    for (int r = 0; r < 4; ++r) {
      int row = lhi * 4 + r;
      float v = fmaxf(acc[n][r] + bv, 0.f);
      ushort_t h = f2b(v);
      ushort_t lo = f2b(v - b2fs(h));
      int sch = (row * 32 + ((col >> 3) ^ (row & 7))) * 8 + (col & 7);
      st1[sch] = h; st1[4096 + sch] = lo;
    }
  }
  __syncthreads();
  // MFMA pass 2
  f32x4 acc2[4];
#pragma unroll
  for (int n = 0; n < 4; ++n) acc2[n] = (f32x4){0.f, 0.f, 0.f, 0.f};
#pragma unroll
  for (int ks = 0; ks < 8; ++ks) {
    int sch = (arow * 32 + ((ks * 4 + lhi) ^ sw)) * 8;
    bf16x8 ah = *(const bf16x8*)&st1[sch];
    bf16x8 al = *(const bf16x8*)&st1[4096 + sch];
#pragma unroll
    for (int n = 0; n < 4; ++n) {
      bf16x8 bb = *(const bf16x8*)(w2P + (size_t)(((ntb + n) * 8 + ks) * 64 + l) * 8);
      acc2[n] = __builtin_amdgcn_mfma_f32_16x16x32_bf16(ah, bb, acc2[n], 0, 0, 0);
      acc2[n] = __builtin_amdgcn_mfma_f32_16x16x32_bf16(al, bb, acc2[n], 0, 0, 0);
    }
  }
#pragma unroll
  for (int n = 0; n < 4; ++n) {
    int col = (ntb + n) * 16 + lrow;
    float bv = cb2v[col];
#pragma unroll
    for (int r = 0; r < 4; ++r)
      outs[(lhi * 4 + r) * 256 + col] = acc2[n][r] + bv;
  }
  __syncthreads();
  // BN + residual + xb write + optional sx refill (reuse sm)
#pragma unroll
  for (int it = 0; it < 4; ++it) {
    int idx = t + it * 256;
    int row = idx >> 6, c4 = idx & 63;
    int grow = row0 + row;
    int c0 = c4 * 4;
    float4 z = *(float4*)&outs[row * 256 + c0];
    float4 g4 = *(const float4*)(bng + c0);
    float4 b4 = *(const float4*)(bnb + c0);
    float4 m4 = *(const float4*)(bnm + c0);
    float4 v4 = *(const float4*)(bnv + c0);
    float4 xv = *(const float4*)(xb + (size_t)grow * H + c0);
    xv.x += fmaxf((z.x - m4.x) * rsqrtf(v4.x + BN_EPS_F) * g4.x + b4.x, 0.f);
    xv.y += fmaxf((z.y - m4.y) * rsqrtf(v4.y + BN_EPS_F) * g4.y + b4.y, 0.f);
    xv.z += fmaxf((z.z - m4.z) * rsqrtf(v4.z + BN_EPS_F) * g4.z + b4.z, 0.f);
    xv.w += fmaxf((z.w - m4.w) * rsqrtf(v4.w + BN_EPS_F) * g4.w + b4.w, 0.f);
    *(float4*)(xb + (size_t)grow * H + c0) = xv;
    if (do_pab) {
      float vv[4] = {xv.x, xv.y, xv.z, xv.w};
      ushort_t h8[4], l8[4];
#pragma unroll
      for (int j = 0; j < 4; ++j) { h8[j] = f2b(vv[j]); l8[j] = f2b(vv[j] - b2fs(h8[j])); }
      ushort4 hh, ll;
      hh.x = h8[0]; hh.y = h8[1]; hh.z = h8[2]; hh.w = h8[3];
      ll.x = l8[0]; ll.y = l8[1]; ll.z = l8[2]; ll.w = l8[3];
      int sch = (row * 32 + ((c0 >> 3) ^ (row & 7))) * 8 + (c0 & 7);
      *(ushort4*)&sm[sch] = hh;
      *(ushort4*)&sm[4096 + sch] = ll;
    }
  }
  if (!do_pab) return;
  __syncthreads();
  const int ntb2 = w * 2;
  f32x4 pacc[2];
#pragma unroll
  for (int n = 0; n < 2; ++n) pacc[n] = (f32x4){0.f, 0.f, 0.f, 0.f};
#pragma unroll
  for (int ks = 0; ks < 8; ++ks) {
    int sch = (arow * 32 + ((ks * 4 + lhi) ^ sw)) * 8;
    bf16x8 ah = *(const bf16x8*)&sm[sch];
    bf16x8 al = *(const bf16x8*)&sm[4096 + sch];
#pragma unroll
    for (int n = 0; n < 2; ++n) {
      bf16x8 bb = *(const bf16x8*)(pabPn + (size_t)(((ntb2 + n) * 8 + ks) * 64 + l) * 8);
      pacc[n] = __builtin_amdgcn_mfma_f32_16x16x32_bf16(ah, bb, pacc[n], 0, 0, 0);
      pacc[n] = __builtin_amdgcn_mfma_f32_16x16x32_bf16(al, bb, pacc[n], 0, 0, 0);
    }
  }
#pragma unroll
  for (int n = 0; n < 2; ++n) {
    int col = (ntb2 + n) * 16 + lrow;
#pragma unroll
    for (int r = 0; r < 4; ++r)
      Pab[(size_t)(row0 + lhi * 4 + r) * 128 + col] = pacc[n][r];
  }
}

// ---------------------------------------------------------------------------
// pooling
// ---------------------------------------------------------------------------
__global__ void k_count2(const int* __restrict__ batch, float* __restrict__ gcnt)
{
  int g = threadIdx.x;
  int lo = 0, hi = NN;
  while (lo < hi) { int m = (lo + hi) >> 1; if (batch[m] < g) lo = m + 1; else hi = m; }
  int s = lo;
  lo = 0; hi = NN;
  while (lo < hi) { int m = (lo + hi) >> 1; if (batch[m] <= g) lo = m + 1; else hi = m; }
  gcnt[g] = (float)(lo - s);
}

__global__ __launch_bounds__(256) void k_pool(const float* __restrict__ xb,
    const int* __restrict__ batch, float* __restrict__ gsum)
{
  const int t = threadIdx.x;
  const int row0 = blockIdx.x * 32;
  const int c0 = (t & 63) * 4;
  const int rb = (t >> 6) * 8;
  float4 sum = make_float4(0.f, 0.f, 0.f, 0.f);
  int curg = -1;
#pragma unroll
  for (int j = 0; j < 8; ++j) {
    int row = row0 + rb + j;
    if (row < NN) {
      int g = batch[row];
      if (g != curg) {
        if (curg >= 0) {
          float* gp = gsum + (size_t)curg * H + c0;
          atomicAdd(gp + 0, sum.x); atomicAdd(gp + 1, sum.y);
          atomicAdd(gp + 2, sum.z); atomicAdd(gp + 3, sum.w);
        }
        curg = g;
        sum = make_float4(0.f, 0.f, 0.f, 0.f);
      }
      float4 v = *(const float4*)(xb + (size_t)row * H + c0);
      sum.x += v.x; sum.y += v.y; sum.z += v.z; sum.w += v.w;
    }
  }
  if (curg >= 0) {
    float* gp = gsum + (size_t)curg * H + c0;
    atomicAdd(gp + 0, sum.x); atomicAdd(gp + 1, sum.y);
    atomicAdd(gp + 2, sum.z); atomicAdd(gp + 3, sum.w);
  }
}

__global__ __launch_bounds__(256) void k_readout(const float* __restrict__ gsum,
    const float* __restrict__ gcnt, const float* __restrict__ w,
    const float* __restrict__ b, float* __restrict__ out)
{
  __shared__ float gs[H];
  const int g = blockIdx.x;
  const int t = threadIdx.x;
  float cnt = fmaxf(gcnt[g], 1.0f);
  gs[t] = gsum[(size_t)g * H + t] / cnt;
  __syncthreads();
  float acc = 0.f;
  for (int k = 0; k < H; ++k) acc += gs[k] * w[(size_t)k * H + t];
  out[(size_t)g * H + t] = fmaxf(acc + b[t], 0.f);
}

// ---------------------------------------------------------------------------
extern "C" void kernel_launch(void* const* d_in, const int* in_sizes, int n_in,
                              void* d_out, int out_size, void* d_ws, size_t ws_size,
                              hipStream_t stream) {
  (void)in_sizes; (void)n_in; (void)out_size; (void)ws_size;
  const float* x    = (const float*)d_in[0];
  const int*   ei   = (const int*)d_in[1];
  const float* ea   = (const float*)d_in[2];
  const int*   batch= (const int*)d_in[3];
  const float* xp_w = (const float*)d_in[4];
  const float* xp_b = (const float*)d_in[5];
  const float* ep_w = (const float*)d_in[6];
  const float* ep_b = (const float*)d_in[7];
  const float* uw1  = (const float*)d_in[8];
  const float* ub1  = (const float*)d_in[9];
  const float* uw2  = (const float*)d_in[10];
  const float* ub2  = (const float*)d_in[11];
  const float* cw1  = (const float*)d_in[12];
  const float* cb1  = (const float*)d_in[13];
  const float* cw2  = (const float*)d_in[14];
  const float* cb2  = (const float*)d_in[15];
  const float* bng  = (const float*)d_in[16];
  const float* bnb  = (const float*)d_in[17];
  const float* bnm  = (const float*)d_in[18];
  const float* bnv  = (const float*)d_in[19];
  const float* ro_w = (const float*)d_in[20];
  const float* ro_b = (const float*)d_in[21];
  float* out = (float*)d_out;

  char* ws = (char*)d_ws;
  float* xb   = (float*)ws;                  ws += (size_t)NN * H * 4;
  float* agg  = (float*)ws;                  ws += (size_t)NN * H * 4;
  float* Pab  = (float*)ws;                  ws += (size_t)NN * 128 * 4;
  float* gsum = (float*)ws;                  ws += (size_t)NG * H * 4;
  float* gcnt = (float*)ws;                  ws += 256;
  ushort_t* e_p = (ushort_t*)ws;             ws += (size_t)NE * H * 2;
  int* deg    = (int*)ws;                    ws += (size_t)NN * 4;
  int* row_ptr= (int*)ws;                    ws += (size_t)(NN + 8) * 4;
  int* cursor = (int*)ws;                    ws += (size_t)NN * 4;
  int* perm   = (int*)ws;                    ws += (size_t)NE * 4;
  int* src_p  = (int*)ws;                    ws += (size_t)NE * 4;
  int* dst_p  = (int*)ws;                    ws += (size_t)NE * 4;
  ushort_t* wcP = (ushort_t*)ws;             ws += (size_t)DEPTH_D * 2048 * 8 * 2;
  ushort_t* w2P = (ushort_t*)ws;             ws += (size_t)DEPTH_D * 2048 * 8 * 2;
  ushort_t* c1P = (ushort_t*)ws;             ws += (size_t)DEPTH_D * 8192 * 8 * 2;
  ushort_t* c2P = (ushort_t*)ws;             ws += (size_t)DEPTH_D * 8192 * 8 * 2;
  ushort_t* pabP= (ushort_t*)ws;             ws += (size_t)DEPTH_D * 4096 * 8 * 2;
  ushort_t* xpP = (ushort_t*)ws;             ws += (size_t)4096 * 8 * 2;

  const int* src = ei;
  const int* dst = ei + NE;
  const int EB = NE / 256;                   // 625

  hipMemsetAsync(deg, 0, (size_t)NN * 4, stream);
  k_hist<<<EB, 256, 0, stream>>>(dst, deg);
  k_scan<<<1, 256, 0, stream>>>(deg, row_ptr, cursor);
  k_scatter<<<EB, 256, 0, stream>>>(src, dst, cursor, perm, src_p, dst_p);
  k_pack_all<<<496, 256, 0, stream>>>(uw1, uw2, cw1, cw2, xp_w,
                                      wcP, w2P, c1P, c2P, pabP, xpP);
  k_projm<<<313, 256, 0, stream>>>(x, xpP, xp_b, pabP, xb, Pab);
  k_proj_edge<<<NE / 16, 256, 0, stream>>>(ea, perm, ep_w, ep_b, e_p);

  for (int i = 0; i < DEPTH_D; ++i) {
    k_edge_mfma<<<NE / 64, 256, 0, stream>>>(
        Pab, src_p, dst_p,
        wcP + (size_t)i * 2048 * 8, ub1 + (size_t)i * UH,
        w2P + (size_t)i * 2048 * 8, ub2 + (size_t)i * H,
        e_p);
    k_agg<<<NN / 4, 256, 0, stream>>>(e_p, xb, src_p, row_ptr, agg);
    int do_pab = (i < DEPTH_D - 1) ? 1 : 0;
    k_convm<<<NN / 16, 256, 0, stream>>>(
        agg,
        c1P + (size_t)i * 8192 * 8, cb1 + (size_t)i * H,
        c2P + (size_t)i * 8192 * 8, cb2 + (size_t)i * H,
        bng + (size_t)i * H, bnb + (size_t)i * H,
        bnm + (size_t)i * H, bnv + (size_t)i * H,
        xb, do_pab,
        pabP + (size_t)(i + 1 < DEPTH_D ? i + 1 : 0) * 4096 * 8,
        Pab);
  }

  hipMemsetAsync(gsum, 0, (size_t)NG * H * 4, stream);
  k_count2<<<1, 64, 0, stream>>>(batch, gcnt);
  k_pool<<<(NN + 31) / 32, 256, 0, stream>>>(xb, batch, gsum);
  k_readout<<<NG, 256, 0, stream>>>(gsum, gcnt, ro_w, ro_b, out);
}